// Round 1
// baseline (918.216 us; speedup 1.0000x reference)
//
#include <hip/hip_runtime.h>
#include <math.h>

#define NROWS 131072
#define SDIM 64
#define HDIM 128
#define KCODES 512
#define ADIM 8

// ---------------------------------------------------------------------------
// k0: ee[k] = sum_j emb[k][j]^2
// ---------------------------------------------------------------------------
__global__ void ee_kernel(const float* __restrict__ emb, float* __restrict__ ee) {
    int k = blockIdx.x * blockDim.x + threadIdx.x;
    if (k >= KCODES) return;
    const float* e = emb + k * HDIM;
    float a0 = 0.f, a1 = 0.f, a2 = 0.f, a3 = 0.f;
#pragma unroll
    for (int j = 0; j < HDIM; j += 4) {
        a0 = fmaf(e[j + 0], e[j + 0], a0);
        a1 = fmaf(e[j + 1], e[j + 1], a1);
        a2 = fmaf(e[j + 2], e[j + 2], a2);
        a3 = fmaf(e[j + 3], e[j + 3], a3);
    }
    ee[k] = (a0 + a1) + (a2 + a3);
}

// ---------------------------------------------------------------------------
// Shared device code: VQ scoring + heads + output write for one row.
// x[] must be the relu'd layer-2 activations, held in registers.
// ---------------------------------------------------------------------------
__device__ __forceinline__ void score_and_heads(
    const float x[HDIM], int row,
    const float* __restrict__ emb, const float* ee,
    const float* __restrict__ Wa, const float* __restrict__ ba,
    const float* __restrict__ Wv, const float* __restrict__ bv,
    float* __restrict__ out)
{
    // vv = ||x||^2
    float v0 = 0.f, v1 = 0.f, v2 = 0.f, v3 = 0.f;
#pragma unroll
    for (int j = 0; j < HDIM; j += 4) {
        v0 = fmaf(x[j + 0], x[j + 0], v0);
        v1 = fmaf(x[j + 1], x[j + 1], v1);
        v2 = fmaf(x[j + 2], x[j + 2], v2);
        v3 = fmaf(x[j + 3], x[j + 3], v3);
    }
    float vv = (v0 + v1) + (v2 + v3);

    float best = 3.402823466e38f;
    int bi = 0;
    for (int k0 = 0; k0 < KCODES; k0 += 4) {
        const float* e0 = emb + (k0 + 0) * HDIM;
        const float* e1 = emb + (k0 + 1) * HDIM;
        const float* e2 = emb + (k0 + 2) * HDIM;
        const float* e3 = emb + (k0 + 3) * HDIM;
        float d0 = 0.f, d1 = 0.f, d2 = 0.f, d3 = 0.f;
#pragma unroll
        for (int j = 0; j < HDIM; ++j) {
            float xj = x[j];
            d0 = fmaf(xj, e0[j], d0);
            d1 = fmaf(xj, e1[j], d1);
            d2 = fmaf(xj, e2[j], d2);
            d3 = fmaf(xj, e3[j], d3);
        }
        // d = (vv - 2*dot) + ee[k]   (mirrors reference expression order)
        float dd0 = (vv - 2.f * d0) + ee[k0 + 0];
        float dd1 = (vv - 2.f * d1) + ee[k0 + 1];
        float dd2 = (vv - 2.f * d2) + ee[k0 + 2];
        float dd3 = (vv - 2.f * d3) + ee[k0 + 3];
        // strict < keeps the FIRST minimal index (jnp.argmin semantics)
        if (dd0 < best) { best = dd0; bi = k0 + 0; }
        if (dd1 < best) { best = dd1; bi = k0 + 1; }
        if (dd2 < best) { best = dd2; bi = k0 + 2; }
        if (dd3 < best) { best = dd3; bi = k0 + 3; }
    }

    // heads: quantize = emb[bi] (forward value of straight-through estimator)
    float lg[ADIM];
#pragma unroll
    for (int a = 0; a < ADIM; ++a) lg[a] = ba[a];
    float val = bv[0];

    const float4* q4 = (const float4*)(emb + bi * HDIM);
#pragma unroll
    for (int j4 = 0; j4 < HDIM / 4; ++j4) {
        float4 q = q4[j4];
        int j = 4 * j4;
#pragma unroll
        for (int a = 0; a < ADIM; ++a) {
            float t = lg[a];
            t = fmaf(q.x, Wa[(j + 0) * ADIM + a], t);
            t = fmaf(q.y, Wa[(j + 1) * ADIM + a], t);
            t = fmaf(q.z, Wa[(j + 2) * ADIM + a], t);
            t = fmaf(q.w, Wa[(j + 3) * ADIM + a], t);
            lg[a] = t;
        }
        val = fmaf(q.x, Wv[j + 0], val);
        val = fmaf(q.y, Wv[j + 1], val);
        val = fmaf(q.z, Wv[j + 2], val);
        val = fmaf(q.w, Wv[j + 3], val);
    }

    float m = lg[0];
#pragma unroll
    for (int a = 1; a < ADIM; ++a) m = fmaxf(m, lg[a]);
    float p[ADIM];
    float s = 0.f;
#pragma unroll
    for (int a = 0; a < ADIM; ++a) { p[a] = __expf(lg[a] - m); s += p[a]; }
    float inv = 1.f / s;

    float4 o0 = make_float4(p[0] * inv, p[1] * inv, p[2] * inv, p[3] * inv);
    float4 o1 = make_float4(p[4] * inv, p[5] * inv, p[6] * inv, p[7] * inv);
    float4* outp = (float4*)(out + (size_t)row * ADIM);
    outp[0] = o0;
    outp[1] = o1;
    out[(size_t)NROWS * ADIM + row] = val;
}

// ---------------------------------------------------------------------------
// k1: layers 1+2 (relu(relu(in@W1+b1)@Wh+bh)) -> x2out, 128 rows per block.
// LDS row layout (stride 129): cols 0..63 input, later overwritten by
// x1[64..127]; cols 64..127 hold x1[0..63]; finally cols 0..127 hold x2.
// ---------------------------------------------------------------------------
__global__ __launch_bounds__(128) void mlp_kernel(
    const float* __restrict__ in,
    const float* __restrict__ W1, const float* __restrict__ b1,
    const float* __restrict__ Wh, const float* __restrict__ bh,
    float* __restrict__ x2out)
{
    __shared__ float lds[128 * 129];
    const int tid = threadIdx.x;
    const int base = blockIdx.x * 128;

    // phase A: coalesced stage of 128x64 input tile
    const float* src = in + (size_t)base * SDIM;
#pragma unroll
    for (int it = 0; it < 64; ++it) {
        int i = tid + 128 * it;       // 0..8191
        int r = i >> 6, c = i & 63;
        lds[r * 129 + c] = src[i];
    }
    __syncthreads();

    float* myrow = &lds[tid * 129];

    // phase B chunk0: x1[0..63] -> cols 64..127
    {
        float acc[64];
#pragma unroll
        for (int j = 0; j < 64; ++j) acc[j] = b1[j];
        for (int s = 0; s < SDIM; ++s) {
            float a = myrow[s];
#pragma unroll
            for (int j = 0; j < 64; ++j) acc[j] = fmaf(a, W1[s * HDIM + j], acc[j]);
        }
#pragma unroll
        for (int j = 0; j < 64; ++j) myrow[64 + j] = fmaxf(acc[j], 0.f);
    }
    // phase B chunk1: x1[64..127] -> cols 0..63 (input dead after this loop)
    {
        float acc[64];
#pragma unroll
        for (int j = 0; j < 64; ++j) acc[j] = b1[64 + j];
        for (int s = 0; s < SDIM; ++s) {
            float a = myrow[s];
#pragma unroll
            for (int j = 0; j < 64; ++j) acc[j] = fmaf(a, W1[s * HDIM + 64 + j], acc[j]);
        }
#pragma unroll
        for (int j = 0; j < 64; ++j) myrow[j] = fmaxf(acc[j], 0.f);
    }

    // phase C: x2 = relu(x1 @ Wh + bh), x1 read from LDS, acc in regs
    float x2[HDIM];
#pragma unroll
    for (int j = 0; j < HDIM; ++j) x2[j] = bh[j];
    for (int t = 0; t < 64; ++t) {
        float a = myrow[64 + t];      // x1[t]
#pragma unroll
        for (int j = 0; j < HDIM; ++j) x2[j] = fmaf(a, Wh[t * HDIM + j], x2[j]);
    }
    for (int t = 0; t < 64; ++t) {
        float a = myrow[t];           // x1[64+t]
#pragma unroll
        for (int j = 0; j < HDIM; ++j) x2[j] = fmaf(a, Wh[(64 + t) * HDIM + j], x2[j]);
    }
#pragma unroll
    for (int j = 0; j < HDIM; ++j) myrow[j] = fmaxf(x2[j], 0.f);
    __syncthreads();

    // phase D: coalesced store of x2 tile
    float* dst = x2out + (size_t)base * HDIM;
#pragma unroll
    for (int it = 0; it < 128; ++it) {
        int o = tid + 128 * it;       // 0..16383
        int r = o >> 7, c = o & 127;
        dst[o] = lds[r * 129 + c];
    }
}

// ---------------------------------------------------------------------------
// k2: VQ scoring + heads, thread per row, x2 row in registers.
// ---------------------------------------------------------------------------
__global__ __launch_bounds__(256, 2) void score_kernel(
    const float* __restrict__ x2in,
    const float* __restrict__ emb, const float* __restrict__ ee,
    const float* __restrict__ Wa, const float* __restrict__ ba,
    const float* __restrict__ Wv, const float* __restrict__ bv,
    float* __restrict__ out)
{
    const int row = blockIdx.x * blockDim.x + threadIdx.x;
    float x[HDIM];
    const float4* xr = (const float4*)(x2in + (size_t)row * HDIM);
#pragma unroll
    for (int j4 = 0; j4 < HDIM / 4; ++j4) {
        float4 v = xr[j4];
        x[4 * j4 + 0] = v.x; x[4 * j4 + 1] = v.y;
        x[4 * j4 + 2] = v.z; x[4 * j4 + 3] = v.w;
    }
    score_and_heads(x, row, emb, ee, Wa, ba, Wv, bv, out);
}

// ---------------------------------------------------------------------------
// Fallback: fully fused (used only if workspace is too small).
// ---------------------------------------------------------------------------
__global__ __launch_bounds__(128) void fused_kernel(
    const float* __restrict__ in,
    const float* __restrict__ W1, const float* __restrict__ b1,
    const float* __restrict__ Wh, const float* __restrict__ bh,
    const float* __restrict__ emb,
    const float* __restrict__ Wa, const float* __restrict__ ba,
    const float* __restrict__ Wv, const float* __restrict__ bv,
    float* __restrict__ out)
{
    __shared__ float lds[128 * 129];
    __shared__ float ee_s[KCODES];
    const int tid = threadIdx.x;
    const int base = blockIdx.x * 128;

    // ee (cooperative, 4 codes per thread)
#pragma unroll
    for (int kk = 0; kk < 4; ++kk) {
        int k = tid + 128 * kk;
        const float* e = emb + k * HDIM;
        float a0 = 0.f, a1 = 0.f, a2 = 0.f, a3 = 0.f;
#pragma unroll
        for (int j = 0; j < HDIM; j += 4) {
            a0 = fmaf(e[j + 0], e[j + 0], a0);
            a1 = fmaf(e[j + 1], e[j + 1], a1);
            a2 = fmaf(e[j + 2], e[j + 2], a2);
            a3 = fmaf(e[j + 3], e[j + 3], a3);
        }
        ee_s[k] = (a0 + a1) + (a2 + a3);
    }

    // input staging
    const float* src = in + (size_t)base * SDIM;
#pragma unroll
    for (int it = 0; it < 64; ++it) {
        int i = tid + 128 * it;
        int r = i >> 6, c = i & 63;
        lds[r * 129 + c] = src[i];
    }
    __syncthreads();

    float* myrow = &lds[tid * 129];
    {
        float acc[64];
#pragma unroll
        for (int j = 0; j < 64; ++j) acc[j] = b1[j];
        for (int s = 0; s < SDIM; ++s) {
            float a = myrow[s];
#pragma unroll
            for (int j = 0; j < 64; ++j) acc[j] = fmaf(a, W1[s * HDIM + j], acc[j]);
        }
#pragma unroll
        for (int j = 0; j < 64; ++j) myrow[64 + j] = fmaxf(acc[j], 0.f);
    }
    {
        float acc[64];
#pragma unroll
        for (int j = 0; j < 64; ++j) acc[j] = b1[64 + j];
        for (int s = 0; s < SDIM; ++s) {
            float a = myrow[s];
#pragma unroll
            for (int j = 0; j < 64; ++j) acc[j] = fmaf(a, W1[s * HDIM + 64 + j], acc[j]);
        }
#pragma unroll
        for (int j = 0; j < 64; ++j) myrow[j] = fmaxf(acc[j], 0.f);
    }

    float x[HDIM];
#pragma unroll
    for (int j = 0; j < HDIM; ++j) x[j] = bh[j];
    for (int t = 0; t < 64; ++t) {
        float a = myrow[64 + t];
#pragma unroll
        for (int j = 0; j < HDIM; ++j) x[j] = fmaf(a, Wh[t * HDIM + j], x[j]);
    }
    for (int t = 0; t < 64; ++t) {
        float a = myrow[t];
#pragma unroll
        for (int j = 0; j < HDIM; ++j) x[j] = fmaf(a, Wh[(64 + t) * HDIM + j], x[j]);
    }
#pragma unroll
    for (int j = 0; j < HDIM; ++j) x[j] = fmaxf(x[j], 0.f);

    score_and_heads(x, base + tid, emb, (const float*)ee_s, Wa, ba, Wv, bv, out);
}

// ---------------------------------------------------------------------------
extern "C" void kernel_launch(void* const* d_in, const int* in_sizes, int n_in,
                              void* d_out, int out_size, void* d_ws, size_t ws_size,
                              hipStream_t stream) {
    const float* in  = (const float*)d_in[0];
    const float* W1  = (const float*)d_in[1];
    const float* b1  = (const float*)d_in[2];
    const float* Wh  = (const float*)d_in[3];
    const float* bh  = (const float*)d_in[4];
    const float* emb = (const float*)d_in[5];
    const float* Wa  = (const float*)d_in[6];
    const float* ba  = (const float*)d_in[7];
    const float* Wv  = (const float*)d_in[8];
    const float* bv  = (const float*)d_in[9];
    float* out = (float*)d_out;

    const size_t x2_bytes = (size_t)NROWS * HDIM * sizeof(float);
    const size_t need = x2_bytes + KCODES * sizeof(float);

    if (ws_size >= need) {
        float* x2ws = (float*)d_ws;
        float* ee   = (float*)d_ws + (size_t)NROWS * HDIM;
        ee_kernel<<<2, 256, 0, stream>>>(emb, ee);
        mlp_kernel<<<NROWS / 128, 128, 0, stream>>>(in, W1, b1, Wh, bh, x2ws);
        score_kernel<<<NROWS / 256, 256, 0, stream>>>(x2ws, emb, ee, Wa, ba, Wv, bv, out);
    } else {
        fused_kernel<<<NROWS / 128, 128, 0, stream>>>(in, W1, b1, Wh, bh, emb,
                                                      Wa, ba, Wv, bv, out);
    }
}

// Round 2
// 853.981 us; speedup vs baseline: 1.0752x; 1.0752x over previous
//
#include <hip/hip_runtime.h>
#include <math.h>

#define NROWS 131072
#define SDIM 64
#define HDIM 128
#define KCODES 512
#define ADIM 8

// ---------------------------------------------------------------------------
// k0: ee[k] = sum_j emb[k][j]^2   (unchanged from round 1 — exact FP order)
// ---------------------------------------------------------------------------
__global__ void ee_kernel(const float* __restrict__ emb, float* __restrict__ ee) {
    int k = blockIdx.x * blockDim.x + threadIdx.x;
    if (k >= KCODES) return;
    const float* e = emb + k * HDIM;
    float a0 = 0.f, a1 = 0.f, a2 = 0.f, a3 = 0.f;
#pragma unroll
    for (int j = 0; j < HDIM; j += 4) {
        a0 = fmaf(e[j + 0], e[j + 0], a0);
        a1 = fmaf(e[j + 1], e[j + 1], a1);
        a2 = fmaf(e[j + 2], e[j + 2], a2);
        a3 = fmaf(e[j + 3], e[j + 3], a3);
    }
    ee[k] = (a0 + a1) + (a2 + a3);
}

// ---------------------------------------------------------------------------
// Scoring + heads as a MACRO so the per-thread x[] array is never passed as a
// pointer (round-1 bug: array-decay at the function call blocked register
// promotion -> x[] lived in scratch -> VALUBusy 38%).
// Requires in scope: emb, Wa, ba, Wv, bv, out.  XARR[j] must be indexable
// with compile-time-constant j (register array or LDS pointer).
// FP evaluation order identical to round 1 (absmax was 0.0).
// ---------------------------------------------------------------------------
#define SCORE_AND_HEADS(XARR, ROW, EEREF)                                     \
  {                                                                           \
    float v0_ = 0.f, v1_ = 0.f, v2_ = 0.f, v3_ = 0.f;                         \
    _Pragma("unroll")                                                         \
    for (int j = 0; j < HDIM; j += 4) {                                       \
        v0_ = fmaf(XARR[j + 0], XARR[j + 0], v0_);                            \
        v1_ = fmaf(XARR[j + 1], XARR[j + 1], v1_);                            \
        v2_ = fmaf(XARR[j + 2], XARR[j + 2], v2_);                            \
        v3_ = fmaf(XARR[j + 3], XARR[j + 3], v3_);                            \
    }                                                                         \
    const float vv_ = (v0_ + v1_) + (v2_ + v3_);                              \
    float best_ = 3.402823466e38f;                                            \
    int bi_ = 0;                                                              \
    for (int k0_ = 0; k0_ < KCODES; k0_ += 8) {                               \
        const float* eb_ = emb + (size_t)k0_ * HDIM;                          \
        float d_[8];                                                          \
        _Pragma("unroll")                                                     \
        for (int c = 0; c < 8; ++c) d_[c] = 0.f;                              \
        _Pragma("unroll")                                                     \
        for (int j = 0; j < HDIM; ++j) {                                      \
            const float xj_ = XARR[j];                                        \
            _Pragma("unroll")                                                 \
            for (int c = 0; c < 8; ++c)                                       \
                d_[c] = fmaf(xj_, eb_[c * HDIM + j], d_[c]);                  \
        }                                                                     \
        _Pragma("unroll")                                                     \
        for (int c = 0; c < 8; ++c) {                                         \
            const float dd_ = (vv_ - 2.f * d_[c]) + EEREF[k0_ + c];           \
            if (dd_ < best_) { best_ = dd_; bi_ = k0_ + c; }                  \
        }                                                                     \
    }                                                                         \
    float lg_[ADIM];                                                          \
    _Pragma("unroll")                                                         \
    for (int a = 0; a < ADIM; ++a) lg_[a] = ba[a];                            \
    float val_ = bv[0];                                                       \
    const float4* q4_ = (const float4*)(emb + (size_t)bi_ * HDIM);            \
    _Pragma("unroll")                                                         \
    for (int j4 = 0; j4 < HDIM / 4; ++j4) {                                   \
        float4 q_ = q4_[j4];                                                  \
        const int j = 4 * j4;                                                 \
        _Pragma("unroll")                                                     \
        for (int a = 0; a < ADIM; ++a) {                                      \
            float t_ = lg_[a];                                                \
            t_ = fmaf(q_.x, Wa[(j + 0) * ADIM + a], t_);                      \
            t_ = fmaf(q_.y, Wa[(j + 1) * ADIM + a], t_);                      \
            t_ = fmaf(q_.z, Wa[(j + 2) * ADIM + a], t_);                      \
            t_ = fmaf(q_.w, Wa[(j + 3) * ADIM + a], t_);                      \
            lg_[a] = t_;                                                      \
        }                                                                     \
        val_ = fmaf(q_.x, Wv[j + 0], val_);                                   \
        val_ = fmaf(q_.y, Wv[j + 1], val_);                                   \
        val_ = fmaf(q_.z, Wv[j + 2], val_);                                   \
        val_ = fmaf(q_.w, Wv[j + 3], val_);                                   \
    }                                                                         \
    float m_ = lg_[0];                                                        \
    _Pragma("unroll")                                                         \
    for (int a = 1; a < ADIM; ++a) m_ = fmaxf(m_, lg_[a]);                    \
    float p_[ADIM];                                                           \
    float s_ = 0.f;                                                           \
    _Pragma("unroll")                                                         \
    for (int a = 0; a < ADIM; ++a) { p_[a] = __expf(lg_[a] - m_); s_ += p_[a]; } \
    const float inv_ = 1.f / s_;                                              \
    float4* outp_ = (float4*)(out + (size_t)(ROW) * ADIM);                    \
    outp_[0] = make_float4(p_[0] * inv_, p_[1] * inv_, p_[2] * inv_, p_[3] * inv_); \
    outp_[1] = make_float4(p_[4] * inv_, p_[5] * inv_, p_[6] * inv_, p_[7] * inv_); \
    out[(size_t)NROWS * ADIM + (ROW)] = val_;                                 \
  }

// ---------------------------------------------------------------------------
// k1: layers 1+2.  Same LDS scheme as round 1 for input + x1, but phase C is
// chunked into two 64-wide register accumulators (no x2[128] array -> no
// spill; VGPR peak ~80) and x2 is stored straight to global as float4
// (L2 write-combines; drops the LDS transpose + second barrier).
// Per-(row,j) FP accumulation order identical to round 1.
// ---------------------------------------------------------------------------
__global__ __launch_bounds__(128) void mlp_kernel(
    const float* __restrict__ in,
    const float* __restrict__ W1, const float* __restrict__ b1,
    const float* __restrict__ Wh, const float* __restrict__ bh,
    float* __restrict__ x2out)
{
    __shared__ float lds[128 * 129];
    const int tid = threadIdx.x;
    const int base = blockIdx.x * 128;

    // phase A: coalesced stage of 128x64 input tile
    const float* src = in + (size_t)base * SDIM;
#pragma unroll
    for (int it = 0; it < 64; ++it) {
        int i = tid + 128 * it;       // 0..8191
        int r = i >> 6, c = i & 63;
        lds[r * 129 + c] = src[i];
    }
    __syncthreads();

    float* myrow = &lds[tid * 129];

    // phase B chunk0: x1[0..63] -> cols 64..127
    {
        float acc[64];
#pragma unroll
        for (int j = 0; j < 64; ++j) acc[j] = b1[j];
        for (int s = 0; s < SDIM; ++s) {
            float a = myrow[s];
#pragma unroll
            for (int j = 0; j < 64; ++j) acc[j] = fmaf(a, W1[s * HDIM + j], acc[j]);
        }
#pragma unroll
        for (int j = 0; j < 64; ++j) myrow[64 + j] = fmaxf(acc[j], 0.f);
    }
    // phase B chunk1: x1[64..127] -> cols 0..63 (input dead after this loop)
    {
        float acc[64];
#pragma unroll
        for (int j = 0; j < 64; ++j) acc[j] = b1[64 + j];
        for (int s = 0; s < SDIM; ++s) {
            float a = myrow[s];
#pragma unroll
            for (int j = 0; j < 64; ++j) acc[j] = fmaf(a, W1[s * HDIM + 64 + j], acc[j]);
        }
#pragma unroll
        for (int j = 0; j < 64; ++j) myrow[j] = fmaxf(acc[j], 0.f);
    }

    // phase C: x2 = relu(x1 @ Wh + bh), two 64-wide chunks, direct store.
    float* dst = x2out + (size_t)(base + tid) * HDIM;
    for (int c = 0; c < 2; ++c) {
        float acc[64];
#pragma unroll
        for (int j = 0; j < 64; ++j) acc[j] = bh[c * 64 + j];
        for (int t = 0; t < 64; ++t) {
            float a = myrow[64 + t];      // x1[t]
#pragma unroll
            for (int j = 0; j < 64; ++j)
                acc[j] = fmaf(a, Wh[t * HDIM + c * 64 + j], acc[j]);
        }
        for (int t = 0; t < 64; ++t) {
            float a = myrow[t];           // x1[64+t]
#pragma unroll
            for (int j = 0; j < 64; ++j)
                acc[j] = fmaf(a, Wh[(64 + t) * HDIM + c * 64 + j], acc[j]);
        }
        float4* d4 = (float4*)(dst + c * 64);
#pragma unroll
        for (int j4 = 0; j4 < 16; ++j4) {
            d4[j4] = make_float4(fmaxf(acc[4 * j4 + 0], 0.f),
                                 fmaxf(acc[4 * j4 + 1], 0.f),
                                 fmaxf(acc[4 * j4 + 2], 0.f),
                                 fmaxf(acc[4 * j4 + 3], 0.f));
        }
    }
}

// ---------------------------------------------------------------------------
// k2: VQ scoring + heads, thread per row, x[128] genuinely in registers.
// __launch_bounds__(256,2): 2 waves/EU min -> 256-VGPR budget (need ~160).
// ---------------------------------------------------------------------------
__global__ __launch_bounds__(256, 2) void score_kernel(
    const float* __restrict__ x2in,
    const float* __restrict__ emb, const float* __restrict__ ee,
    const float* __restrict__ Wa, const float* __restrict__ ba,
    const float* __restrict__ Wv, const float* __restrict__ bv,
    float* __restrict__ out)
{
    const int row = blockIdx.x * blockDim.x + threadIdx.x;
    float x[HDIM];
    const float4* xr = (const float4*)(x2in + (size_t)row * HDIM);
#pragma unroll
    for (int j4 = 0; j4 < HDIM / 4; ++j4) {
        float4 v = xr[j4];
        x[4 * j4 + 0] = v.x; x[4 * j4 + 1] = v.y;
        x[4 * j4 + 2] = v.z; x[4 * j4 + 3] = v.w;
    }
    SCORE_AND_HEADS(x, row, ee)
}

// ---------------------------------------------------------------------------
// Fallback: fully fused (only if workspace too small; never ran in round 1).
// mlp phase kept in LDS; score reads x directly from the LDS row.
// ---------------------------------------------------------------------------
__global__ __launch_bounds__(128) void fused_kernel(
    const float* __restrict__ in,
    const float* __restrict__ W1, const float* __restrict__ b1,
    const float* __restrict__ Wh, const float* __restrict__ bh,
    const float* __restrict__ emb,
    const float* __restrict__ Wa, const float* __restrict__ ba,
    const float* __restrict__ Wv, const float* __restrict__ bv,
    float* __restrict__ out)
{
    __shared__ float lds[128 * 129];
    __shared__ float ee_s[KCODES];
    const int tid = threadIdx.x;
    const int base = blockIdx.x * 128;

#pragma unroll
    for (int kk = 0; kk < 4; ++kk) {
        int k = tid + 128 * kk;
        const float* e = emb + k * HDIM;
        float a0 = 0.f, a1 = 0.f, a2 = 0.f, a3 = 0.f;
#pragma unroll
        for (int j = 0; j < HDIM; j += 4) {
            a0 = fmaf(e[j + 0], e[j + 0], a0);
            a1 = fmaf(e[j + 1], e[j + 1], a1);
            a2 = fmaf(e[j + 2], e[j + 2], a2);
            a3 = fmaf(e[j + 3], e[j + 3], a3);
        }
        ee_s[k] = (a0 + a1) + (a2 + a3);
    }

    const float* src = in + (size_t)base * SDIM;
#pragma unroll
    for (int it = 0; it < 64; ++it) {
        int i = tid + 128 * it;
        int r = i >> 6, c = i & 63;
        lds[r * 129 + c] = src[i];
    }
    __syncthreads();

    float* myrow = &lds[tid * 129];
    {
        float acc[64];
#pragma unroll
        for (int j = 0; j < 64; ++j) acc[j] = b1[j];
        for (int s = 0; s < SDIM; ++s) {
            float a = myrow[s];
#pragma unroll
            for (int j = 0; j < 64; ++j) acc[j] = fmaf(a, W1[s * HDIM + j], acc[j]);
        }
#pragma unroll
        for (int j = 0; j < 64; ++j) myrow[64 + j] = fmaxf(acc[j], 0.f);
    }
    {
        float acc[64];
#pragma unroll
        for (int j = 0; j < 64; ++j) acc[j] = b1[64 + j];
        for (int s = 0; s < SDIM; ++s) {
            float a = myrow[s];
#pragma unroll
            for (int j = 0; j < 64; ++j) acc[j] = fmaf(a, W1[s * HDIM + 64 + j], acc[j]);
        }
#pragma unroll
        for (int j = 0; j < 64; ++j) myrow[j] = fmaxf(acc[j], 0.f);
    }

    // x2 chunks held in registers (accA/accB), then written back to myrow.
    float accA[64], accB[64];
#pragma unroll
    for (int j = 0; j < 64; ++j) accA[j] = bh[j];
#pragma unroll
    for (int j = 0; j < 64; ++j) accB[j] = bh[64 + j];
    for (int t = 0; t < 64; ++t) {
        float a = myrow[64 + t];
#pragma unroll
        for (int j = 0; j < 64; ++j) accA[j] = fmaf(a, Wh[t * HDIM + j], accA[j]);
#pragma unroll
        for (int j = 0; j < 64; ++j) accB[j] = fmaf(a, Wh[t * HDIM + 64 + j], accB[j]);
    }
    for (int t = 0; t < 64; ++t) {
        float a = myrow[t];
#pragma unroll
        for (int j = 0; j < 64; ++j) accA[j] = fmaf(a, Wh[(64 + t) * HDIM + j], accA[j]);
#pragma unroll
        for (int j = 0; j < 64; ++j) accB[j] = fmaf(a, Wh[(64 + t) * HDIM + 64 + j], accB[j]);
    }
#pragma unroll
    for (int j = 0; j < 64; ++j) myrow[j] = fmaxf(accA[j], 0.f);
#pragma unroll
    for (int j = 0; j < 64; ++j) myrow[64 + j] = fmaxf(accB[j], 0.f);

    SCORE_AND_HEADS(myrow, base + tid, ee_s)
}

// ---------------------------------------------------------------------------
extern "C" void kernel_launch(void* const* d_in, const int* in_sizes, int n_in,
                              void* d_out, int out_size, void* d_ws, size_t ws_size,
                              hipStream_t stream) {
    const float* in  = (const float*)d_in[0];
    const float* W1  = (const float*)d_in[1];
    const float* b1  = (const float*)d_in[2];
    const float* Wh  = (const float*)d_in[3];
    const float* bh  = (const float*)d_in[4];
    const float* emb = (const float*)d_in[5];
    const float* Wa  = (const float*)d_in[6];
    const float* ba  = (const float*)d_in[7];
    const float* Wv  = (const float*)d_in[8];
    const float* bv  = (const float*)d_in[9];
    float* out = (float*)d_out;

    const size_t x2_bytes = (size_t)NROWS * HDIM * sizeof(float);
    const size_t need = x2_bytes + KCODES * sizeof(float);

    if (ws_size >= need) {
        float* x2ws = (float*)d_ws;
        float* ee   = (float*)d_ws + (size_t)NROWS * HDIM;
        ee_kernel<<<2, 256, 0, stream>>>(emb, ee);
        mlp_kernel<<<NROWS / 128, 128, 0, stream>>>(in, W1, b1, Wh, bh, x2ws);
        score_kernel<<<NROWS / 256, 256, 0, stream>>>(x2ws, emb, ee, Wa, ba, Wv, bv, out);
    } else {
        fused_kernel<<<NROWS / 128, 128, 0, stream>>>(in, W1, b1, Wh, bh, emb,
                                                      Wa, ba, Wv, bv, out);
    }
}